// Round 3
// baseline (180.618 us; speedup 1.0000x reference)
//
#include <hip/hip_runtime.h>
#include <hip/hip_bf16.h>

// p1,p2 : (B=2, C=32, D=H=W=64) fp32. Pool 4x4x4 -> S=16, N = 8192 rows of C=32.
// loss = ||A Aᵀ - B Bᵀ||_F² / N² = (||AᵀA||² - 2||AᵀB||² + ||BᵀB||²) / N²
// with only 32x32 Grams. Reformulation verified exact (absmax 0.0) rounds 1-2.

#define HW   4096      // 64*64
#define DHW  262144    // 64*64*64
#define NROW 8192
#define C    32

__device__ __forceinline__ float4 f4add(const float4 a, const float4 b) {
    return make_float4(a.x + b.x, a.y + b.y, a.z + b.z, a.w + b.w);
}

// ---------------------------------------------------------------------------
// Kernel 1: 4x4x4 avg-pool. One block per (arr, b, c, zp): 2048 blocks, each
// reads a contiguous 64 KiB slab. ILP fix vs round 2: loads are staged into an
// explicit 8-deep float4 register batch BEFORE accumulation (2 batches), so 8
// loads stay in flight per wave (~58 VGPR, still 8 waves/SIMD). Chain j sums
// p ∈ {j, j+4, j+8, j+12} — identical value sets to the verified round-2 code.
// Block 0 additionally zeroes the 3072-float Gram buffer + completion counter
// (replaces the hipMemsetAsync node).
// ---------------------------------------------------------------------------
__global__ __launch_bounds__(256) void pool_kernel(
    const float* __restrict__ p1, const float* __restrict__ p2,
    float* __restrict__ Pa, float* __restrict__ Pb, float* __restrict__ G)
{
    const int tid = threadIdx.x;
    const int bid = blockIdx.x;

    if (bid == 0) {
        #pragma unroll
        for (int i = 0; i < 13; ++i) {
            const int idx = tid + i * 256;
            if (idx < 3136) G[idx] = 0.f;     // Gaa|Gab|Gbb (3072) + counter + pad
        }
    }

    const int zp  = bid & 15;
    const int c   = (bid >> 4) & 31;
    const int b   = (bid >> 9) & 1;
    const int arr = bid >> 10;

    const float* __restrict__ src = arr ? p2 : p1;
    float* __restrict__ dst       = arr ? Pb : Pa;

    const float4* __restrict__ base = reinterpret_cast<const float4*>(
        src + (size_t)(b * C + c) * DHW + (size_t)(zp * 4) * HW);

    const int lane = tid & 63;
    const int w    = tid >> 6;

    __shared__ float pool[256];   // [yp*16 + xw]

    float4 v[8], acc[4];
    #pragma unroll
    for (int p = 0; p < 8; ++p) v[p] = base[p * 256 + tid];          // 8 in flight
    #pragma unroll
    for (int j = 0; j < 4; ++j) acc[j] = f4add(v[j], v[j + 4]);
    #pragma unroll
    for (int p = 0; p < 8; ++p) v[p] = base[(p + 8) * 256 + tid];    // 8 in flight
    #pragma unroll
    for (int j = 0; j < 4; ++j) acc[j] = f4add(acc[j], f4add(v[j], v[j + 4]));

    #pragma unroll
    for (int j = 0; j < 4; ++j) {
        float s = (acc[j].x + acc[j].y) + (acc[j].z + acc[j].w);
        s += __shfl_xor(s, 16);          // reduce over dy = lane>>4
        s += __shfl_xor(s, 32);
        const int yp = (4 * j + w) & 15;
        if (lane < 16) pool[yp * 16 + lane] = s * (1.0f / 64.0f);
    }
    __syncthreads();

    const int n = b * 4096 + zp * 256 + tid;   // row index
    dst[(size_t)n * C + c] = pool[tid];
}

// ---------------------------------------------------------------------------
// Kernel 2: fused row-normalize + three 32x32 Grams + last-block finalize.
// 256 blocks x 256 threads, 32 rows/block. Thread t's staging float4 IS the
// (row=t>>3, cols=(t&7)*4) fragment -> row norm via shfl_xor(1,2,4), scale in
// register, LDS stage, 12-accumulator register Gram, one atomicAdd set.
// Then: __syncthreads (drains this block's device-scope atomics) -> ticket on
// a completion counter -> last block reduces G (agent-scope atomic loads) and
// writes the scalar loss. Removes the separate finalize kernel node.
// ---------------------------------------------------------------------------
__global__ __launch_bounds__(256) void gram_kernel(
    const float* __restrict__ Pa, const float* __restrict__ Pb,
    float* __restrict__ G,   // [0..1023]=Gaa, [1024..2047]=Gab, [2048..3071]=Gbb, [3072]=counter
    float* __restrict__ out)
{
    const int tid = threadIdx.x;
    const int k  = tid >> 3;          // 0..31
    const int l4 = (tid & 7) * 4;     // 0,4,...,28

    __shared__ float As[32 * C];
    __shared__ float Bs[32 * C];

    const int r = blockIdx.x * 32;
    float4 va = reinterpret_cast<const float4*>(Pa + (size_t)r * C)[tid];
    float4 vb = reinterpret_cast<const float4*>(Pb + (size_t)r * C)[tid];

    float ssa = va.x*va.x + va.y*va.y + va.z*va.z + va.w*va.w;
    float ssb = vb.x*vb.x + vb.y*vb.y + vb.z*vb.z + vb.w*vb.w;
    ssa += __shfl_xor(ssa, 1); ssa += __shfl_xor(ssa, 2); ssa += __shfl_xor(ssa, 4);
    ssb += __shfl_xor(ssb, 1); ssb += __shfl_xor(ssb, 2); ssb += __shfl_xor(ssb, 4);
    const float inva = 1.0f / fmaxf(sqrtf(ssa), 1e-8f);
    const float invb = 1.0f / fmaxf(sqrtf(ssb), 1e-8f);
    va.x *= inva; va.y *= inva; va.z *= inva; va.w *= inva;
    vb.x *= invb; vb.y *= invb; vb.z *= invb; vb.w *= invb;

    reinterpret_cast<float4*>(As)[tid] = va;
    reinterpret_cast<float4*>(Bs)[tid] = vb;
    __syncthreads();

    float gaa[4] = {0.f, 0.f, 0.f, 0.f};
    float gab[4] = {0.f, 0.f, 0.f, 0.f};
    float gbb[4] = {0.f, 0.f, 0.f, 0.f};

    #pragma unroll
    for (int i = 0; i < 32; ++i) {
        const float a_k = As[i * C + k];
        const float b_k = Bs[i * C + k];
        const float4 a_l = *reinterpret_cast<const float4*>(&As[i * C + l4]);
        const float4 b_l = *reinterpret_cast<const float4*>(&Bs[i * C + l4]);
        gaa[0] += a_k * a_l.x;  gaa[1] += a_k * a_l.y;
        gaa[2] += a_k * a_l.z;  gaa[3] += a_k * a_l.w;
        gab[0] += a_k * b_l.x;  gab[1] += a_k * b_l.y;
        gab[2] += a_k * b_l.z;  gab[3] += a_k * b_l.w;
        gbb[0] += b_k * b_l.x;  gbb[1] += b_k * b_l.y;
        gbb[2] += b_k * b_l.z;  gbb[3] += b_k * b_l.w;
    }

    #pragma unroll
    for (int j = 0; j < 4; ++j) {
        atomicAdd(&G[k * C + l4 + j],        gaa[j]);
        atomicAdd(&G[1024 + k * C + l4 + j], gab[j]);
        atomicAdd(&G[2048 + k * C + l4 + j], gbb[j]);
    }

    // ---- last-block finalize ----
    __syncthreads();   // s_waitcnt vmcnt(0) before barrier drains our atomics
    __shared__ int last_flag;
    if (tid == 0) {
        __threadfence();
        const unsigned t = __hip_atomic_fetch_add(
            reinterpret_cast<unsigned*>(G + 3072), 1u,
            __ATOMIC_ACQ_REL, __HIP_MEMORY_SCOPE_AGENT);
        last_flag = (t == (unsigned)(gridDim.x - 1));
    }
    __syncthreads();
    if (!last_flag) return;

    float vv = 0.f;
    #pragma unroll
    for (int e0 = 0; e0 < 1024; e0 += 256) {
        const int e = e0 + tid;
        const float gA = __hip_atomic_load(G + e,        __ATOMIC_RELAXED, __HIP_MEMORY_SCOPE_AGENT);
        const float gX = __hip_atomic_load(G + 1024 + e, __ATOMIC_RELAXED, __HIP_MEMORY_SCOPE_AGENT);
        const float gB = __hip_atomic_load(G + 2048 + e, __ATOMIC_RELAXED, __HIP_MEMORY_SCOPE_AGENT);
        vv += gA * gA + gB * gB - 2.f * gX * gX;
    }
    vv += __shfl_xor(vv, 1);  vv += __shfl_xor(vv, 2);  vv += __shfl_xor(vv, 4);
    vv += __shfl_xor(vv, 8);  vv += __shfl_xor(vv, 16); vv += __shfl_xor(vv, 32);

    __shared__ float red[4];
    if ((tid & 63) == 0) red[tid >> 6] = vv;
    __syncthreads();
    if (tid == 0)
        out[0] = (red[0] + red[1] + red[2] + red[3]) * (1.0f / ((float)NROW * (float)NROW));
}

extern "C" void kernel_launch(void* const* d_in, const int* in_sizes, int n_in,
                              void* d_out, int out_size, void* d_ws, size_t ws_size,
                              hipStream_t stream) {
    const float* p1 = (const float*)d_in[0];
    const float* p2 = (const float*)d_in[1];
    float* out = (float*)d_out;

    float* Pa = (float*)d_ws;                    // 8192*32 floats = 1 MiB (unnormalized)
    float* Pb = Pa + (size_t)NROW * C;           // 1 MiB
    float* G  = Pb + (size_t)NROW * C;           // 3*1024 floats + counter

    pool_kernel<<<2048, 256, 0, stream>>>(p1, p2, Pa, Pb, G);
    gram_kernel<<<256, 256, 0, stream>>>(Pa, Pb, G, out);
}